// Round 4
// baseline (50377.853 us; speedup 1.0000x reference)
//
#include <hip/hip_runtime.h>
#include <hip/hip_bf16.h>

// V=50000, E=1600000, D=64, EF=16, node_in=74, NV=64 (derived at launch).
// Flat-tile design:
//   CSR (dst-sorted) built once; tiles of 16 edges with tileInfo{p0,nrows}.
//   edge_tile: ptile[t] = colsum over tile rows of relu([h[src],ea,1]@W1')
//     where W1' row 80 = b1 (flag-bias trick -> masked rows contribute 0).
//   ln_node:  S[u] = sum of ptile rows in [firstTile[u],firstTile[u+1]);
//             h' = LN(h + (S@W2)/deg + b2 [deg>0]).

typedef __attribute__((ext_vector_type(8))) short short8b;   // 8 bf16
typedef __attribute__((ext_vector_type(4))) float f32x4;     // MFMA C/D
typedef __attribute__((ext_vector_type(4))) unsigned int u32x4;

static __device__ __forceinline__ short f2bf(float f) {
  union { __hip_bfloat16 h; short s; } u; u.h = __float2bfloat16(f); return u.s;
}
static __device__ __forceinline__ float bf2f(short s) {
  union { unsigned u; float f; } v; v.u = ((unsigned)(unsigned short)s) << 16; return v.f;
}
static __device__ __forceinline__ short8b zero8() {
  short8b z;
#pragma unroll
  for (int i = 0; i < 8; ++i) z[i] = 0;
  return z;
}
static __device__ __forceinline__ short8b and8(short8b a, unsigned m) {
  u32x4 x = __builtin_bit_cast(u32x4, a);
#pragma unroll
  for (int i = 0; i < 4; ++i) x[i] &= m;
  return __builtin_bit_cast(short8b, x);
}

// ------------------------------------------------------------ CSR build
__global__ void deg_kernel(const int* __restrict__ ei, int* __restrict__ deg, int E_) {
  int i = blockIdx.x * blockDim.x + threadIdx.x;
  if (i < E_) atomicAdd(&deg[ei[E_ + i]], 1);
}

__global__ void off_kernel(const int* __restrict__ deg, int* __restrict__ off,
                           int* __restrict__ cursor, int* __restrict__ firstTile,
                           int* __restrict__ gtot, int V_) {
  int v = blockIdx.x * blockDim.x + threadIdx.x;
  int lane = threadIdx.x & 63;
  int d = (v < V_) ? deg[v] : 0;
  int td = (d + 15) >> 4;
  int x = d, y = td;
#pragma unroll
  for (int o = 1; o < 64; o <<= 1) {
    int xu = __shfl_up(x, o), yu = __shfl_up(y, o);
    if (lane >= o) { x += xu; y += yu; }
  }
  int totE = __shfl(x, 63), totT = __shfl(y, 63);
  int exE = x - d, exT = y - td;
  int baseE = 0, baseT = 0;
  if (lane == 0) {
    baseE = atomicAdd(&gtot[0], totE);
    baseT = atomicAdd(&gtot[1], totT);
  }
  baseE = __shfl(baseE, 0); baseT = __shfl(baseT, 0);
  if (v < V_) {
    off[v] = baseE + exE; cursor[v] = baseE + exE; firstTile[v] = baseT + exT;
  }
}

__global__ void tile_fill_kernel(const int* __restrict__ deg, const int* __restrict__ off,
                                 int* __restrict__ firstTile, int2* __restrict__ tinfo,
                                 const int* __restrict__ gtot, int V_) {
  int v = blockIdx.x * blockDim.x + threadIdx.x;
  if (v == V_) firstTile[V_] = gtot[1];
  if (v >= V_) return;
  int d = deg[v], o = off[v], T0 = firstTile[v];
  int nt = (d + 15) >> 4;
  for (int j = 0; j < nt; ++j)
    tinfo[T0 + j] = make_int2(o + 16 * j, min(16, d - 16 * j));
}

__global__ void scatter_kernel(const int* __restrict__ ei, const float* __restrict__ ea,
                               int* __restrict__ cursor, int* __restrict__ srcs,
                               short* __restrict__ eas, int E_) {
  int i = blockIdx.x * blockDim.x + threadIdx.x;
  if (i >= E_) return;
  int dst = ei[E_ + i];
  int pos = atomicAdd(&cursor[dst], 1);
  srcs[pos] = ei[i];
  const float4* row = reinterpret_cast<const float4*>(ea + (size_t)i * 16);
  float4 q0 = row[0], q1 = row[1], q2 = row[2], q3 = row[3];
  short8b s0, s1;
  s0[0]=f2bf(q0.x); s0[1]=f2bf(q0.y); s0[2]=f2bf(q0.z); s0[3]=f2bf(q0.w);
  s0[4]=f2bf(q1.x); s0[5]=f2bf(q1.y); s0[6]=f2bf(q1.z); s0[7]=f2bf(q1.w);
  s1[0]=f2bf(q2.x); s1[1]=f2bf(q2.y); s1[2]=f2bf(q2.z); s1[3]=f2bf(q2.w);
  s1[4]=f2bf(q3.x); s1[5]=f2bf(q3.y); s1[6]=f2bf(q3.z); s1[7]=f2bf(q3.w);
  short8b* out = reinterpret_cast<short8b*>(eas + (size_t)pos * 16);
  out[0] = s0; out[1] = s1;
}

// ------------------------------------------------------- embed (MFMA tiles)
__global__ __launch_bounds__(256) void embed_mfma(
    const float* __restrict__ Z, const float* __restrict__ vm,
    const float* __restrict__ nW, const float* __restrict__ nb,
    float* __restrict__ h, short* __restrict__ hbf, int V_) {
  const int lane = threadIdx.x & 63;
  const int r = lane & 15, g = lane >> 4;
  short8b wf[4][3];
#pragma unroll
  for (int n = 0; n < 4; ++n)
#pragma unroll
    for (int s = 0; s < 3; ++s)
#pragma unroll
      for (int i = 0; i < 8; ++i) {
        int k = s * 32 + 8 * g + i;
        wf[n][s][i] = f2bf(k < 74 ? nW[k * 64 + n * 16 + r] : 0.0f);
      }
  float nb4[4];
#pragma unroll
  for (int n = 0; n < 4; ++n) nb4[n] = nb[n * 16 + r];

  const int ntiles = (V_ + 15) >> 4;
  const int nw = (gridDim.x * blockDim.x) >> 6;
  const int w0 = (blockIdx.x * blockDim.x + threadIdx.x) >> 6;
  for (int tile = w0; tile < ntiles; tile += nw) {
    const int v0 = tile << 4;
    const int vr = min(v0 + r, V_ - 1);
    const float4* z4 = reinterpret_cast<const float4*>(Z + (size_t)vr * 64);
    float4 p0 = z4[2 * g], p1 = z4[2 * g + 1];
    float4 p2 = z4[8 + 2 * g], p3 = z4[9 + 2 * g];
    short8b a0, a1, a2 = zero8();
    a0[0]=f2bf(p0.x); a0[1]=f2bf(p0.y); a0[2]=f2bf(p0.z); a0[3]=f2bf(p0.w);
    a0[4]=f2bf(p1.x); a0[5]=f2bf(p1.y); a0[6]=f2bf(p1.z); a0[7]=f2bf(p1.w);
    a1[0]=f2bf(p2.x); a1[1]=f2bf(p2.y); a1[2]=f2bf(p2.z); a1[3]=f2bf(p2.w);
    a1[4]=f2bf(p3.x); a1[5]=f2bf(p3.y); a1[6]=f2bf(p3.z); a1[7]=f2bf(p3.w);
    const float* vrow = vm + (size_t)vr * 10;
    if (g == 0) {
#pragma unroll
      for (int i = 0; i < 8; ++i) a2[i] = f2bf(vrow[i]);
    } else if (g == 1) {
      a2[0] = f2bf(vrow[8]); a2[1] = f2bf(vrow[9]);
    }
    f32x4 acc[4];
#pragma unroll
    for (int n = 0; n < 4; ++n) {
      acc[n] = f32x4{nb4[n], nb4[n], nb4[n], nb4[n]};
      acc[n] = __builtin_amdgcn_mfma_f32_16x16x32_bf16(a0, wf[n][0], acc[n], 0, 0, 0);
      acc[n] = __builtin_amdgcn_mfma_f32_16x16x32_bf16(a1, wf[n][1], acc[n], 0, 0, 0);
      acc[n] = __builtin_amdgcn_mfma_f32_16x16x32_bf16(a2, wf[n][2], acc[n], 0, 0, 0);
    }
#pragma unroll
    for (int i = 0; i < 4; ++i) {
      int u = v0 + 4 * g + i;
      if (u < V_) {
#pragma unroll
        for (int n = 0; n < 4; ++n) {
          h[(size_t)u * 64 + n * 16 + r] = acc[n][i];
          hbf[(size_t)u * 64 + n * 16 + r] = f2bf(acc[n][i]);
        }
      }
    }
  }
}

// ---------------------------------------------------- edge tile kernel
// Grid-stride over flat tile stream; 2-deep prefetch pipeline.
__global__ __launch_bounds__(256) void edge_tile_kernel(
    const short* __restrict__ hbf, const int* __restrict__ srcs,
    const short* __restrict__ eas, const int2* __restrict__ tinfo,
    const int* __restrict__ gtot,
    const float* __restrict__ W1, const float* __restrict__ b1,
    short* __restrict__ ptile, int V_, int E_) {
  const int lane = threadIdx.x & 63;
  const int r = lane & 15, g = lane >> 4;
  // W1' fragments: rows 0..79 = W1, row 80 = b1, rows 81..95 = 0
  short8b w1f[4][3];
#pragma unroll
  for (int n = 0; n < 4; ++n)
#pragma unroll
    for (int s = 0; s < 3; ++s)
#pragma unroll
      for (int i = 0; i < 8; ++i) {
        int k = s * 32 + 8 * g + i;
        float wv = (k < 80) ? W1[k * 64 + n * 16 + r]
                 : (k == 80 ? b1[n * 16 + r] : 0.0f);
        w1f[n][s][i] = f2bf(wv);
      }
  const int ntiles = gtot[1];
  const int nw = (gridDim.x * blockDim.x) >> 6;
  int t = (blockIdx.x * blockDim.x + threadIdx.x) >> 6;
  if (t >= ntiles) return;
  // prologue: tile t info + loads, tile t+nw info
  int2 tc = tinfo[t];
  int tn_i = t + nw;
  int2 tn = (tn_i < ntiles) ? tinfo[tn_i] : tc;
  int pc = min(tc.x + r, E_ - 1);
  int srcv = srcs[pc];
  short8b eav = zero8();
  if (g < 2) eav = *reinterpret_cast<const short8b*>(eas + (size_t)pc * 16 + 8 * g);

  while (true) {
    // gathers for current tile (srcv loaded last iteration)
    const short* hrow = hbf + (size_t)srcv * 64;
    short8b a0 = *reinterpret_cast<const short8b*>(hrow + 8 * g);
    short8b a1 = *reinterpret_cast<const short8b*>(hrow + 32 + 8 * g);
    // prefetch: tileinfo 2 ahead, srcs/eas 1 ahead
    int t2_i = tn_i + nw;
    int2 t2 = (t2_i < ntiles) ? tinfo[t2_i] : tn;
    int pn = min(tn.x + r, E_ - 1);
    int srcn = srcs[pn];
    short8b ean = zero8();
    if (g < 2) ean = *reinterpret_cast<const short8b*>(eas + (size_t)pn * 16 + 8 * g);
    // tail masking (rows >= nrows must be all-zero)
    unsigned m = (r < tc.y) ? 0xFFFFFFFFu : 0u;
    a0 = and8(a0, m);
    a1 = and8(a1, m);
    short8b a2 = zero8();
    if (g < 2) a2 = and8(eav, m);
    if (g == 2) a2[0] = (short)(m & 0x3F80u);  // flag feature = 1.0bf16
    // GEMM1: 16x96 @ 96x64
    f32x4 acc[4];
#pragma unroll
    for (int n = 0; n < 4; ++n) {
      acc[n] = f32x4{0.f, 0.f, 0.f, 0.f};
      acc[n] = __builtin_amdgcn_mfma_f32_16x16x32_bf16(a0, w1f[n][0], acc[n], 0, 0, 0);
      acc[n] = __builtin_amdgcn_mfma_f32_16x16x32_bf16(a1, w1f[n][1], acc[n], 0, 0, 0);
      acc[n] = __builtin_amdgcn_mfma_f32_16x16x32_bf16(a2, w1f[n][2], acc[n], 0, 0, 0);
    }
    // relu + sum over 16 rows
    float s4[4];
#pragma unroll
    for (int n = 0; n < 4; ++n) {
      float s = (fmaxf(acc[n][0], 0.f) + fmaxf(acc[n][1], 0.f))
              + (fmaxf(acc[n][2], 0.f) + fmaxf(acc[n][3], 0.f));
      s += __shfl_xor(s, 16);
      s += __shfl_xor(s, 32);
      s4[n] = s;
    }
    float val = (g & 2) ? ((g & 1) ? s4[3] : s4[2]) : ((g & 1) ? s4[1] : s4[0]);
    ptile[(size_t)t * 64 + 16 * g + r] = f2bf(val);
    // rotate pipeline
    t = tn_i;
    if (t >= ntiles) break;
    tn_i = t2_i; tc = tn; tn = t2; srcv = srcn; eav = ean;
  }
}

// -------------------------------------------------- node GEMM + LN kernel
__global__ __launch_bounds__(256) void ln_node_kernel(
    const short* __restrict__ ptile, const int* __restrict__ firstTile,
    const float* __restrict__ h_in, const int* __restrict__ deg,
    const float* __restrict__ W2, const float* __restrict__ b2,
    const float* __restrict__ gam, const float* __restrict__ bet,
    float* __restrict__ h_out, short* __restrict__ hbf_out, int V_) {
  const int lane = threadIdx.x & 63;
  const int r = lane & 15, g = lane >> 4;
  short8b w2f[4][2];
#pragma unroll
  for (int n = 0; n < 4; ++n)
#pragma unroll
    for (int s = 0; s < 2; ++s)
#pragma unroll
      for (int i = 0; i < 8; ++i) {
        int k = s * 32 + 8 * g + i;
        w2f[n][s][i] = f2bf(W2[k * 64 + n * 16 + r]);
      }
  float b2v[4], gv[4], bv[4];
#pragma unroll
  for (int n = 0; n < 4; ++n) {
    b2v[n] = b2[n * 16 + r]; gv[n] = gam[n * 16 + r]; bv[n] = bet[n * 16 + r];
  }
  const int ntile16 = (V_ + 15) >> 4;
  const int nw = (gridDim.x * blockDim.x) >> 6;
  const int w0 = (blockIdx.x * blockDim.x + threadIdx.x) >> 6;
  for (int tile = w0; tile < ntile16; tile += nw) {
    const int v0 = tile << 4;
    const int u = min(v0 + r, V_ - 1);
    const int t0 = firstTile[u], t1 = firstTile[u + 1];
    float sum0[8], sum1[8];
#pragma unroll
    for (int i = 0; i < 8; ++i) { sum0[i] = 0.f; sum1[i] = 0.f; }
    for (int tt = t0; tt < t1; ++tt) {
      const short* prow = ptile + (size_t)tt * 64;
      short8b q0 = *reinterpret_cast<const short8b*>(prow + 8 * g);
      short8b q1 = *reinterpret_cast<const short8b*>(prow + 32 + 8 * g);
#pragma unroll
      for (int i = 0; i < 8; ++i) { sum0[i] += bf2f(q0[i]); sum1[i] += bf2f(q1[i]); }
    }
    short8b a0, a1;
#pragma unroll
    for (int i = 0; i < 8; ++i) { a0[i] = f2bf(sum0[i]); a1[i] = f2bf(sum1[i]); }
    f32x4 acc[4];
#pragma unroll
    for (int n = 0; n < 4; ++n) {
      acc[n] = f32x4{0.f, 0.f, 0.f, 0.f};
      acc[n] = __builtin_amdgcn_mfma_f32_16x16x32_bf16(a0, w2f[n][0], acc[n], 0, 0, 0);
      acc[n] = __builtin_amdgcn_mfma_f32_16x16x32_bf16(a1, w2f[n][1], acc[n], 0, 0, 0);
    }
    float x[4][4];  // [i][n]
    float pm[4], pq[4];
#pragma unroll
    for (int i = 0; i < 4; ++i) {
      int u2 = min(v0 + 4 * g + i, V_ - 1);
      int di = deg[u2];
      float inv = di > 0 ? 1.0f / (float)di : 0.0f;
      float hasb = di > 0 ? 1.0f : 0.0f;
      float s = 0.f, q = 0.f;
#pragma unroll
      for (int n = 0; n < 4; ++n) {
        float hv = h_in[(size_t)u2 * 64 + n * 16 + r];
        float xx = hv + acc[n][i] * inv + hasb * b2v[n];
        x[i][n] = xx;
        s += xx; q += xx * xx;
      }
      pm[i] = s; pq[i] = q;
    }
#pragma unroll
    for (int o = 1; o < 16; o <<= 1) {
#pragma unroll
      for (int i = 0; i < 4; ++i) {
        pm[i] += __shfl_xor(pm[i], o);
        pq[i] += __shfl_xor(pq[i], o);
      }
    }
#pragma unroll
    for (int i = 0; i < 4; ++i) {
      int u2 = v0 + 4 * g + i;
      if (u2 < V_) {
        float mean = pm[i] * (1.0f / 64.0f);
        float var = pq[i] * (1.0f / 64.0f) - mean * mean;
        float rs = rsqrtf(var + 1e-5f);
#pragma unroll
        for (int n = 0; n < 4; ++n) {
          float y = (x[i][n] - mean) * rs * gv[n] + bv[n];
          h_out[(size_t)u2 * 64 + n * 16 + r] = y;
          if (hbf_out) hbf_out[(size_t)u2 * 64 + n * 16 + r] = f2bf(y);
        }
      }
    }
  }
}

// ------------------------------------------------------------- props kernel
__global__ void props_kernel(const float* __restrict__ vf,
                             const float* __restrict__ pW1, const float* __restrict__ pb1,
                             const float* __restrict__ pW2, const float* __restrict__ pb2,
                             float* __restrict__ props) {
  __shared__ float tbuf[64];
  const int c = threadIdx.x;  // 0..63
  float w1c[8], w2c[64];
#pragma unroll
  for (int i = 0; i < 8; ++i) w1c[i] = pW1[i * 64 + c];
#pragma unroll
  for (int k = 0; k < 64; ++k) w2c[k] = pW2[k * 64 + c];
  const float b1c = pb1[c], b2c = pb2[c];
  for (int v = 0; v < 64; ++v) {
    float acc = b1c;
#pragma unroll
    for (int i = 0; i < 8; ++i) acc = fmaf(vf[v * 8 + i], w1c[i], acc);
    tbuf[c] = fmaxf(acc, 0.0f);
    __syncthreads();
    float s = b2c;
#pragma unroll
    for (int k = 0; k < 64; ++k) s = fmaf(tbuf[k], w2c[k], s);
    props[v * 64 + c] = s;
    __syncthreads();
  }
}

// -------------------------------------------------------------- final kernel
__global__ void final_kernel(const float* __restrict__ h, const int* __restrict__ cur,
                             const float* __restrict__ props,
                             const float* __restrict__ rg, const float* __restrict__ rb,
                             float* __restrict__ out) {
  const int v = blockIdx.x;
  const int c = threadIdx.x;  // 64 threads
  const int node = cur[v];
  float x = h[(size_t)node * 64 + c] + props[v * 64 + c];
  float m = x;
#pragma unroll
  for (int off = 32; off; off >>= 1) m += __shfl_xor(m, off);
  m *= (1.0f / 64.0f);
  float d = x - m;
  float var = d * d;
#pragma unroll
  for (int off = 32; off; off >>= 1) var += __shfl_xor(var, off);
  var *= (1.0f / 64.0f);
  out[v * 64 + c] = d * rsqrtf(var + 1e-5f) * rg[c] + rb[c];
}

extern "C" void kernel_launch(void* const* d_in, const int* in_sizes, int n_in,
                              void* d_out, int out_size, void* d_ws, size_t ws_size,
                              hipStream_t stream) {
  const float* Z   = (const float*)d_in[0];
  const float* vm  = (const float*)d_in[1];
  const float* vf  = (const float*)d_in[2];
  const float* ea  = (const float*)d_in[3];
  const int*   ei  = (const int*)d_in[4];
  const int*   cur = (const int*)d_in[5];
  const float* nW  = (const float*)d_in[6];
  const float* nb  = (const float*)d_in[7];
  const float* pW1 = (const float*)d_in[8];
  const float* pb1 = (const float*)d_in[9];
  const float* pW2 = (const float*)d_in[10];
  const float* pb2 = (const float*)d_in[11];
  const float* rg  = (const float*)d_in[12];
  const float* rb  = (const float*)d_in[13];
  const float* W1[2] = {(const float*)d_in[14], (const float*)d_in[20]};
  const float* B1[2] = {(const float*)d_in[15], (const float*)d_in[21]};
  const float* W2[2] = {(const float*)d_in[16], (const float*)d_in[22]};
  const float* B2[2] = {(const float*)d_in[17], (const float*)d_in[23]};
  const float* G[2]  = {(const float*)d_in[18], (const float*)d_in[24]};
  const float* BE[2] = {(const float*)d_in[19], (const float*)d_in[25]};

  const int V_ = in_sizes[0] / 64;
  const int E_ = in_sizes[4] / 2;
  const int NTMAX = (E_ >> 4) + V_;  // >= sum(ceil(deg/16))
  float* out = (float*)d_out;

  char* p = (char*)d_ws;
  auto take = [&](size_t bytes) { char* q = p; p += (bytes + 255) & ~(size_t)255; return q; };
  float* hA      = (float*)take((size_t)V_ * 64 * 4);
  float* hB      = (float*)take((size_t)V_ * 64 * 4);
  short* hAbf    = (short*)take((size_t)V_ * 64 * 2);
  short* hBbf    = (short*)take((size_t)V_ * 64 * 2);
  int*   srcs    = (int*)take((size_t)E_ * 4);
  short* eas     = (short*)take((size_t)E_ * 16 * 2);
  short* ptile   = (short*)take((size_t)NTMAX * 64 * 2);
  int2*  tinfo   = (int2*)take((size_t)NTMAX * 8);
  int*   deg     = (int*)take((size_t)V_ * 4);
  int*   off     = (int*)take((size_t)V_ * 4);
  int*   cursor  = (int*)take((size_t)V_ * 4);
  int*   firstT  = (int*)take((size_t)(V_ + 1) * 4);
  int*   gtot    = (int*)take(256);
  float* props   = (float*)take(64 * 64 * 4);

  // ---- CSR + tile stream build (once; shared by both layers)
  hipMemsetAsync(deg, 0, (size_t)V_ * 4, stream);
  hipMemsetAsync(gtot, 0, 256, stream);
  deg_kernel<<<(E_ + 255) / 256, 256, 0, stream>>>(ei, deg, E_);
  off_kernel<<<(V_ + 255) / 256, 256, 0, stream>>>(deg, off, cursor, firstT, gtot, V_);
  tile_fill_kernel<<<(V_ + 256) / 256, 256, 0, stream>>>(deg, off, firstT, tinfo, gtot, V_);
  scatter_kernel<<<(E_ + 255) / 256, 256, 0, stream>>>(ei, ea, cursor, srcs, eas, E_);

  // ---- embed + props
  embed_mfma<<<784, 256, 0, stream>>>(Z, vm, nW, nb, hA, hAbf, V_);
  props_kernel<<<1, 64, 0, stream>>>(vf, pW1, pb1, pW2, pb2, props);

  // ---- layer 0
  edge_tile_kernel<<<2048, 256, 0, stream>>>(hAbf, srcs, eas, tinfo, gtot,
                                             W1[0], B1[0], ptile, V_, E_);
  ln_node_kernel<<<784, 256, 0, stream>>>(ptile, firstT, hA, deg, W2[0], B2[0],
                                          G[0], BE[0], hB, hBbf, V_);

  // ---- layer 1
  edge_tile_kernel<<<2048, 256, 0, stream>>>(hBbf, srcs, eas, tinfo, gtot,
                                             W1[1], B1[1], ptile, V_, E_);
  ln_node_kernel<<<784, 256, 0, stream>>>(ptile, firstT, hB, deg, W2[1], B2[1],
                                          G[1], BE[1], hA, (short*)nullptr, V_);

  final_kernel<<<64, 64, 0, stream>>>(hA, cur, props, rg, rb, out);
}

// Round 5
// 416.130 us; speedup vs baseline: 121.0628x; 121.0628x over previous
//
#include <hip/hip_runtime.h>
#include <hip/hip_bf16.h>

// V=50000, E=1600000, D=64, EF=16, node_in=74, NV=64 (derived at launch).
// Flat-tile design:
//   CSR (dst-sorted) built once; tiles of 16 edges with tileInfo{p0,nrows}.
//   edge_tile: ptile[t] = colsum over tile rows of relu([h[src],ea,1]@W1')
//     where W1' row 80 = b1 (flag-bias trick -> masked rows contribute 0).
//   ln_node:  S[u] = sum of ptile rows in [firstTile[u], firstTile[u]+ceil(deg/16));
//             h' = LN(h + (S@W2)/deg + b2 [deg>0]).
// NOTE: tile allocations are per-wave-atomic, NOT monotonic in node order, so
// the per-node range length MUST come from deg[u], never firstTile[u+1].

typedef __attribute__((ext_vector_type(8))) short short8b;   // 8 bf16
typedef __attribute__((ext_vector_type(4))) float f32x4;     // MFMA C/D
typedef __attribute__((ext_vector_type(4))) unsigned int u32x4;

static __device__ __forceinline__ short f2bf(float f) {
  union { __hip_bfloat16 h; short s; } u; u.h = __float2bfloat16(f); return u.s;
}
static __device__ __forceinline__ float bf2f(short s) {
  union { unsigned u; float f; } v; v.u = ((unsigned)(unsigned short)s) << 16; return v.f;
}
static __device__ __forceinline__ short8b zero8() {
  short8b z;
#pragma unroll
  for (int i = 0; i < 8; ++i) z[i] = 0;
  return z;
}
static __device__ __forceinline__ short8b and8(short8b a, unsigned m) {
  u32x4 x = __builtin_bit_cast(u32x4, a);
#pragma unroll
  for (int i = 0; i < 4; ++i) x[i] &= m;
  return __builtin_bit_cast(short8b, x);
}

// ------------------------------------------------------------ CSR build
__global__ void deg_kernel(const int* __restrict__ ei, int* __restrict__ deg, int E_) {
  int i = blockIdx.x * blockDim.x + threadIdx.x;
  if (i < E_) atomicAdd(&deg[ei[E_ + i]], 1);
}

__global__ void off_kernel(const int* __restrict__ deg, int* __restrict__ off,
                           int* __restrict__ cursor, int* __restrict__ firstTile,
                           int* __restrict__ gtot, int V_) {
  int v = blockIdx.x * blockDim.x + threadIdx.x;
  int lane = threadIdx.x & 63;
  int d = (v < V_) ? deg[v] : 0;
  int td = (d + 15) >> 4;
  int x = d, y = td;
#pragma unroll
  for (int o = 1; o < 64; o <<= 1) {
    int xu = __shfl_up(x, o), yu = __shfl_up(y, o);
    if (lane >= o) { x += xu; y += yu; }
  }
  int totE = __shfl(x, 63), totT = __shfl(y, 63);
  int exE = x - d, exT = y - td;
  int baseE = 0, baseT = 0;
  if (lane == 0) {
    baseE = atomicAdd(&gtot[0], totE);
    baseT = atomicAdd(&gtot[1], totT);
  }
  baseE = __shfl(baseE, 0); baseT = __shfl(baseT, 0);
  if (v < V_) {
    off[v] = baseE + exE; cursor[v] = baseE + exE; firstTile[v] = baseT + exT;
  }
}

__global__ void tile_fill_kernel(const int* __restrict__ deg, const int* __restrict__ off,
                                 const int* __restrict__ firstTile, int2* __restrict__ tinfo,
                                 int V_) {
  int v = blockIdx.x * blockDim.x + threadIdx.x;
  if (v >= V_) return;
  int d = deg[v], o = off[v], T0 = firstTile[v];
  int nt = (d + 15) >> 4;
  for (int j = 0; j < nt; ++j)
    tinfo[T0 + j] = make_int2(o + 16 * j, min(16, d - 16 * j));
}

__global__ void scatter_kernel(const int* __restrict__ ei, const float* __restrict__ ea,
                               int* __restrict__ cursor, int* __restrict__ srcs,
                               short* __restrict__ eas, int E_) {
  int i = blockIdx.x * blockDim.x + threadIdx.x;
  if (i >= E_) return;
  int dst = ei[E_ + i];
  int pos = atomicAdd(&cursor[dst], 1);
  srcs[pos] = ei[i];
  const float4* row = reinterpret_cast<const float4*>(ea + (size_t)i * 16);
  float4 q0 = row[0], q1 = row[1], q2 = row[2], q3 = row[3];
  short8b s0, s1;
  s0[0]=f2bf(q0.x); s0[1]=f2bf(q0.y); s0[2]=f2bf(q0.z); s0[3]=f2bf(q0.w);
  s0[4]=f2bf(q1.x); s0[5]=f2bf(q1.y); s0[6]=f2bf(q1.z); s0[7]=f2bf(q1.w);
  s1[0]=f2bf(q2.x); s1[1]=f2bf(q2.y); s1[2]=f2bf(q2.z); s1[3]=f2bf(q2.w);
  s1[4]=f2bf(q3.x); s1[5]=f2bf(q3.y); s1[6]=f2bf(q3.z); s1[7]=f2bf(q3.w);
  short8b* out = reinterpret_cast<short8b*>(eas + (size_t)pos * 16);
  out[0] = s0; out[1] = s1;
}

// ------------------------------------------------------- embed (MFMA tiles)
__global__ __launch_bounds__(256) void embed_mfma(
    const float* __restrict__ Z, const float* __restrict__ vm,
    const float* __restrict__ nW, const float* __restrict__ nb,
    float* __restrict__ h, short* __restrict__ hbf, int V_) {
  const int lane = threadIdx.x & 63;
  const int r = lane & 15, g = lane >> 4;
  short8b wf[4][3];
#pragma unroll
  for (int n = 0; n < 4; ++n)
#pragma unroll
    for (int s = 0; s < 3; ++s)
#pragma unroll
      for (int i = 0; i < 8; ++i) {
        int k = s * 32 + 8 * g + i;
        wf[n][s][i] = f2bf(k < 74 ? nW[k * 64 + n * 16 + r] : 0.0f);
      }
  float nb4[4];
#pragma unroll
  for (int n = 0; n < 4; ++n) nb4[n] = nb[n * 16 + r];

  const int ntiles = (V_ + 15) >> 4;
  const int nw = (gridDim.x * blockDim.x) >> 6;
  const int w0 = (blockIdx.x * blockDim.x + threadIdx.x) >> 6;
  for (int tile = w0; tile < ntiles; tile += nw) {
    const int v0 = tile << 4;
    const int vr = min(v0 + r, V_ - 1);
    const float4* z4 = reinterpret_cast<const float4*>(Z + (size_t)vr * 64);
    float4 p0 = z4[2 * g], p1 = z4[2 * g + 1];
    float4 p2 = z4[8 + 2 * g], p3 = z4[9 + 2 * g];
    short8b a0, a1, a2 = zero8();
    a0[0]=f2bf(p0.x); a0[1]=f2bf(p0.y); a0[2]=f2bf(p0.z); a0[3]=f2bf(p0.w);
    a0[4]=f2bf(p1.x); a0[5]=f2bf(p1.y); a0[6]=f2bf(p1.z); a0[7]=f2bf(p1.w);
    a1[0]=f2bf(p2.x); a1[1]=f2bf(p2.y); a1[2]=f2bf(p2.z); a1[3]=f2bf(p2.w);
    a1[4]=f2bf(p3.x); a1[5]=f2bf(p3.y); a1[6]=f2bf(p3.z); a1[7]=f2bf(p3.w);
    const float* vrow = vm + (size_t)vr * 10;
    if (g == 0) {
#pragma unroll
      for (int i = 0; i < 8; ++i) a2[i] = f2bf(vrow[i]);
    } else if (g == 1) {
      a2[0] = f2bf(vrow[8]); a2[1] = f2bf(vrow[9]);
    }
    f32x4 acc[4];
#pragma unroll
    for (int n = 0; n < 4; ++n) {
      acc[n] = f32x4{nb4[n], nb4[n], nb4[n], nb4[n]};
      acc[n] = __builtin_amdgcn_mfma_f32_16x16x32_bf16(a0, wf[n][0], acc[n], 0, 0, 0);
      acc[n] = __builtin_amdgcn_mfma_f32_16x16x32_bf16(a1, wf[n][1], acc[n], 0, 0, 0);
      acc[n] = __builtin_amdgcn_mfma_f32_16x16x32_bf16(a2, wf[n][2], acc[n], 0, 0, 0);
    }
#pragma unroll
    for (int i = 0; i < 4; ++i) {
      int u = v0 + 4 * g + i;
      if (u < V_) {
#pragma unroll
        for (int n = 0; n < 4; ++n) {
          h[(size_t)u * 64 + n * 16 + r] = acc[n][i];
          hbf[(size_t)u * 64 + n * 16 + r] = f2bf(acc[n][i]);
        }
      }
    }
  }
}

// ---------------------------------------------------- edge tile kernel
// Grid-stride over flat tile stream; 2-deep prefetch pipeline.
__global__ __launch_bounds__(256) void edge_tile_kernel(
    const short* __restrict__ hbf, const int* __restrict__ srcs,
    const short* __restrict__ eas, const int2* __restrict__ tinfo,
    const int* __restrict__ gtot,
    const float* __restrict__ W1, const float* __restrict__ b1,
    short* __restrict__ ptile, int V_, int E_) {
  const int lane = threadIdx.x & 63;
  const int r = lane & 15, g = lane >> 4;
  // W1' fragments: rows 0..79 = W1, row 80 = b1, rows 81..95 = 0
  short8b w1f[4][3];
#pragma unroll
  for (int n = 0; n < 4; ++n)
#pragma unroll
    for (int s = 0; s < 3; ++s)
#pragma unroll
      for (int i = 0; i < 8; ++i) {
        int k = s * 32 + 8 * g + i;
        float wv = (k < 80) ? W1[k * 64 + n * 16 + r]
                 : (k == 80 ? b1[n * 16 + r] : 0.0f);
        w1f[n][s][i] = f2bf(wv);
      }
  const int ntiles = gtot[1];
  const int nw = (gridDim.x * blockDim.x) >> 6;
  int t = (blockIdx.x * blockDim.x + threadIdx.x) >> 6;
  if (t >= ntiles) return;
  // prologue: tile t info + loads, tile t+nw info
  int2 tc = tinfo[t];
  int tn_i = t + nw;
  int2 tn = (tn_i < ntiles) ? tinfo[tn_i] : tc;
  int pc = min(tc.x + r, E_ - 1);
  int srcv = srcs[pc];
  short8b eav = zero8();
  if (g < 2) eav = *reinterpret_cast<const short8b*>(eas + (size_t)pc * 16 + 8 * g);

  while (true) {
    // gathers for current tile (srcv loaded last iteration)
    const short* hrow = hbf + (size_t)srcv * 64;
    short8b a0 = *reinterpret_cast<const short8b*>(hrow + 8 * g);
    short8b a1 = *reinterpret_cast<const short8b*>(hrow + 32 + 8 * g);
    // prefetch: tileinfo 2 ahead, srcs/eas 1 ahead
    int t2_i = tn_i + nw;
    int2 t2 = (t2_i < ntiles) ? tinfo[t2_i] : tn;
    int pn = min(tn.x + r, E_ - 1);
    int srcn = srcs[pn];
    short8b ean = zero8();
    if (g < 2) ean = *reinterpret_cast<const short8b*>(eas + (size_t)pn * 16 + 8 * g);
    // tail masking (rows >= nrows must be all-zero)
    unsigned m = (r < tc.y) ? 0xFFFFFFFFu : 0u;
    a0 = and8(a0, m);
    a1 = and8(a1, m);
    short8b a2 = zero8();
    if (g < 2) a2 = and8(eav, m);
    if (g == 2) a2[0] = (short)(m & 0x3F80u);  // flag feature = 1.0bf16
    // GEMM1: 16x96 @ 96x64
    f32x4 acc[4];
#pragma unroll
    for (int n = 0; n < 4; ++n) {
      acc[n] = f32x4{0.f, 0.f, 0.f, 0.f};
      acc[n] = __builtin_amdgcn_mfma_f32_16x16x32_bf16(a0, w1f[n][0], acc[n], 0, 0, 0);
      acc[n] = __builtin_amdgcn_mfma_f32_16x16x32_bf16(a1, w1f[n][1], acc[n], 0, 0, 0);
      acc[n] = __builtin_amdgcn_mfma_f32_16x16x32_bf16(a2, w1f[n][2], acc[n], 0, 0, 0);
    }
    // relu + sum over 16 rows
    float s4[4];
#pragma unroll
    for (int n = 0; n < 4; ++n) {
      float s = (fmaxf(acc[n][0], 0.f) + fmaxf(acc[n][1], 0.f))
              + (fmaxf(acc[n][2], 0.f) + fmaxf(acc[n][3], 0.f));
      s += __shfl_xor(s, 16);
      s += __shfl_xor(s, 32);
      s4[n] = s;
    }
    float val = (g & 2) ? ((g & 1) ? s4[3] : s4[2]) : ((g & 1) ? s4[1] : s4[0]);
    ptile[(size_t)t * 64 + 16 * g + r] = f2bf(val);
    // rotate pipeline
    t = tn_i;
    if (t >= ntiles) break;
    tn_i = t2_i; tc = tn; tn = t2; srcv = srcn; eav = ean;
  }
}

// -------------------------------------------------- node GEMM + LN kernel
// Per-node tile range = [firstTile[u], firstTile[u] + ceil(deg[u]/16)).
__global__ __launch_bounds__(256) void ln_node_kernel(
    const short* __restrict__ ptile, const int* __restrict__ firstTile,
    const float* __restrict__ h_in, const int* __restrict__ deg,
    const float* __restrict__ W2, const float* __restrict__ b2,
    const float* __restrict__ gam, const float* __restrict__ bet,
    float* __restrict__ h_out, short* __restrict__ hbf_out, int V_) {
  const int lane = threadIdx.x & 63;
  const int r = lane & 15, g = lane >> 4;
  short8b w2f[4][2];
#pragma unroll
  for (int n = 0; n < 4; ++n)
#pragma unroll
    for (int s = 0; s < 2; ++s)
#pragma unroll
      for (int i = 0; i < 8; ++i) {
        int k = s * 32 + 8 * g + i;
        w2f[n][s][i] = f2bf(W2[k * 64 + n * 16 + r]);
      }
  float b2v[4], gv[4], bv[4];
#pragma unroll
  for (int n = 0; n < 4; ++n) {
    b2v[n] = b2[n * 16 + r]; gv[n] = gam[n * 16 + r]; bv[n] = bet[n * 16 + r];
  }
  const int ntile16 = (V_ + 15) >> 4;
  const int nw = (gridDim.x * blockDim.x) >> 6;
  const int w0 = (blockIdx.x * blockDim.x + threadIdx.x) >> 6;
  for (int tile = w0; tile < ntile16; tile += nw) {
    const int v0 = tile << 4;
    const int u = min(v0 + r, V_ - 1);
    const int t0 = firstTile[u];
    const int t1 = t0 + ((deg[u] + 15) >> 4);   // local count — NOT firstTile[u+1]
    float sum0[8], sum1[8];
#pragma unroll
    for (int i = 0; i < 8; ++i) { sum0[i] = 0.f; sum1[i] = 0.f; }
    for (int tt = t0; tt < t1; ++tt) {
      const short* prow = ptile + (size_t)tt * 64;
      short8b q0 = *reinterpret_cast<const short8b*>(prow + 8 * g);
      short8b q1 = *reinterpret_cast<const short8b*>(prow + 32 + 8 * g);
#pragma unroll
      for (int i = 0; i < 8; ++i) { sum0[i] += bf2f(q0[i]); sum1[i] += bf2f(q1[i]); }
    }
    short8b a0, a1;
#pragma unroll
    for (int i = 0; i < 8; ++i) { a0[i] = f2bf(sum0[i]); a1[i] = f2bf(sum1[i]); }
    f32x4 acc[4];
#pragma unroll
    for (int n = 0; n < 4; ++n) {
      acc[n] = f32x4{0.f, 0.f, 0.f, 0.f};
      acc[n] = __builtin_amdgcn_mfma_f32_16x16x32_bf16(a0, w2f[n][0], acc[n], 0, 0, 0);
      acc[n] = __builtin_amdgcn_mfma_f32_16x16x32_bf16(a1, w2f[n][1], acc[n], 0, 0, 0);
    }
    float x[4][4];  // [i][n]
    float pm[4], pq[4];
#pragma unroll
    for (int i = 0; i < 4; ++i) {
      int u2 = min(v0 + 4 * g + i, V_ - 1);
      int di = deg[u2];
      float inv = di > 0 ? 1.0f / (float)di : 0.0f;
      float hasb = di > 0 ? 1.0f : 0.0f;
      float s = 0.f, q = 0.f;
#pragma unroll
      for (int n = 0; n < 4; ++n) {
        float hv = h_in[(size_t)u2 * 64 + n * 16 + r];
        float xx = hv + acc[n][i] * inv + hasb * b2v[n];
        x[i][n] = xx;
        s += xx; q += xx * xx;
      }
      pm[i] = s; pq[i] = q;
    }
#pragma unroll
    for (int o = 1; o < 16; o <<= 1) {
#pragma unroll
      for (int i = 0; i < 4; ++i) {
        pm[i] += __shfl_xor(pm[i], o);
        pq[i] += __shfl_xor(pq[i], o);
      }
    }
#pragma unroll
    for (int i = 0; i < 4; ++i) {
      int u2 = v0 + 4 * g + i;
      if (u2 < V_) {
        float mean = pm[i] * (1.0f / 64.0f);
        float var = pq[i] * (1.0f / 64.0f) - mean * mean;
        float rs = rsqrtf(var + 1e-5f);
#pragma unroll
        for (int n = 0; n < 4; ++n) {
          float y = (x[i][n] - mean) * rs * gv[n] + bv[n];
          h_out[(size_t)u2 * 64 + n * 16 + r] = y;
          if (hbf_out) hbf_out[(size_t)u2 * 64 + n * 16 + r] = f2bf(y);
        }
      }
    }
  }
}

// ------------------------------------------------------------- props kernel
__global__ void props_kernel(const float* __restrict__ vf,
                             const float* __restrict__ pW1, const float* __restrict__ pb1,
                             const float* __restrict__ pW2, const float* __restrict__ pb2,
                             float* __restrict__ props) {
  __shared__ float tbuf[64];
  const int c = threadIdx.x;  // 0..63
  float w1c[8], w2c[64];
#pragma unroll
  for (int i = 0; i < 8; ++i) w1c[i] = pW1[i * 64 + c];
#pragma unroll
  for (int k = 0; k < 64; ++k) w2c[k] = pW2[k * 64 + c];
  const float b1c = pb1[c], b2c = pb2[c];
  for (int v = 0; v < 64; ++v) {
    float acc = b1c;
#pragma unroll
    for (int i = 0; i < 8; ++i) acc = fmaf(vf[v * 8 + i], w1c[i], acc);
    tbuf[c] = fmaxf(acc, 0.0f);
    __syncthreads();
    float s = b2c;
#pragma unroll
    for (int k = 0; k < 64; ++k) s = fmaf(tbuf[k], w2c[k], s);
    props[v * 64 + c] = s;
    __syncthreads();
  }
}

// -------------------------------------------------------------- final kernel
__global__ void final_kernel(const float* __restrict__ h, const int* __restrict__ cur,
                             const float* __restrict__ props,
                             const float* __restrict__ rg, const float* __restrict__ rb,
                             float* __restrict__ out) {
  const int v = blockIdx.x;
  const int c = threadIdx.x;  // 64 threads
  const int node = cur[v];
  float x = h[(size_t)node * 64 + c] + props[v * 64 + c];
  float m = x;
#pragma unroll
  for (int off = 32; off; off >>= 1) m += __shfl_xor(m, off);
  m *= (1.0f / 64.0f);
  float d = x - m;
  float var = d * d;
#pragma unroll
  for (int off = 32; off; off >>= 1) var += __shfl_xor(var, off);
  var *= (1.0f / 64.0f);
  out[v * 64 + c] = d * rsqrtf(var + 1e-5f) * rg[c] + rb[c];
}

extern "C" void kernel_launch(void* const* d_in, const int* in_sizes, int n_in,
                              void* d_out, int out_size, void* d_ws, size_t ws_size,
                              hipStream_t stream) {
  const float* Z   = (const float*)d_in[0];
  const float* vm  = (const float*)d_in[1];
  const float* vf  = (const float*)d_in[2];
  const float* ea  = (const float*)d_in[3];
  const int*   ei  = (const int*)d_in[4];
  const int*   cur = (const int*)d_in[5];
  const float* nW  = (const float*)d_in[6];
  const float* nb  = (const float*)d_in[7];
  const float* pW1 = (const float*)d_in[8];
  const float* pb1 = (const float*)d_in[9];
  const float* pW2 = (const float*)d_in[10];
  const float* pb2 = (const float*)d_in[11];
  const float* rg  = (const float*)d_in[12];
  const float* rb  = (const float*)d_in[13];
  const float* W1[2] = {(const float*)d_in[14], (const float*)d_in[20]};
  const float* B1[2] = {(const float*)d_in[15], (const float*)d_in[21]};
  const float* W2[2] = {(const float*)d_in[16], (const float*)d_in[22]};
  const float* B2[2] = {(const float*)d_in[17], (const float*)d_in[23]};
  const float* G[2]  = {(const float*)d_in[18], (const float*)d_in[24]};
  const float* BE[2] = {(const float*)d_in[19], (const float*)d_in[25]};

  const int V_ = in_sizes[0] / 64;
  const int E_ = in_sizes[4] / 2;
  const int NTMAX = (E_ >> 4) + V_;  // >= sum(ceil(deg/16))
  float* out = (float*)d_out;

  char* p = (char*)d_ws;
  auto take = [&](size_t bytes) { char* q = p; p += (bytes + 255) & ~(size_t)255; return q; };
  float* hA      = (float*)take((size_t)V_ * 64 * 4);
  float* hB      = (float*)take((size_t)V_ * 64 * 4);
  short* hAbf    = (short*)take((size_t)V_ * 64 * 2);
  short* hBbf    = (short*)take((size_t)V_ * 64 * 2);
  int*   srcs    = (int*)take((size_t)E_ * 4);
  short* eas     = (short*)take((size_t)E_ * 16 * 2);
  short* ptile   = (short*)take((size_t)NTMAX * 64 * 2);
  int2*  tinfo   = (int2*)take((size_t)NTMAX * 8);
  int*   deg     = (int*)take((size_t)V_ * 4);
  int*   off     = (int*)take((size_t)V_ * 4);
  int*   cursor  = (int*)take((size_t)V_ * 4);
  int*   firstT  = (int*)take((size_t)(V_ + 1) * 4);
  int*   gtot    = (int*)take(256);
  float* props   = (float*)take(64 * 64 * 4);

  // ---- CSR + tile stream build (once; shared by both layers)
  hipMemsetAsync(deg, 0, (size_t)V_ * 4, stream);
  hipMemsetAsync(gtot, 0, 256, stream);
  deg_kernel<<<(E_ + 255) / 256, 256, 0, stream>>>(ei, deg, E_);
  off_kernel<<<(V_ + 255) / 256, 256, 0, stream>>>(deg, off, cursor, firstT, gtot, V_);
  tile_fill_kernel<<<(V_ + 255) / 256, 256, 0, stream>>>(deg, off, firstT, tinfo, V_);
  scatter_kernel<<<(E_ + 255) / 256, 256, 0, stream>>>(ei, ea, cursor, srcs, eas, E_);

  // ---- embed + props
  embed_mfma<<<784, 256, 0, stream>>>(Z, vm, nW, nb, hA, hAbf, V_);
  props_kernel<<<1, 64, 0, stream>>>(vf, pW1, pb1, pW2, pb2, props);

  // ---- layer 0
  edge_tile_kernel<<<2048, 256, 0, stream>>>(hAbf, srcs, eas, tinfo, gtot,
                                             W1[0], B1[0], ptile, V_, E_);
  ln_node_kernel<<<784, 256, 0, stream>>>(ptile, firstT, hA, deg, W2[0], B2[0],
                                          G[0], BE[0], hB, hBbf, V_);

  // ---- layer 1
  edge_tile_kernel<<<2048, 256, 0, stream>>>(hBbf, srcs, eas, tinfo, gtot,
                                             W1[1], B1[1], ptile, V_, E_);
  ln_node_kernel<<<784, 256, 0, stream>>>(ptile, firstT, hB, deg, W2[1], B2[1],
                                          G[1], BE[1], hA, (short*)nullptr, V_);

  final_kernel<<<64, 64, 0, stream>>>(hA, cur, props, rg, rb, out);
}